// Round 6
// baseline (642.301 us; speedup 1.0000x reference)
//
#include <hip/hip_runtime.h>
#include <hip/hip_fp16.h>

#define NN 100000
#define EE 1600000
#define HH 64
#define GG 64
#define NBK 391    // buckets of 256 nodes: dst>>8
#define CAP 8192   // fixed bucket capacity (mean load 4092, max ~4400)

// ---------------- workspace layout (bytes) ----------------
// rowStart : int[NN]          @ 0
// rowLen   : int[NN]          @ 400000
// dinv     : float[NN]        @ 800000
// srcs     : int[NBK*CAP]     @ 1200000   (bucket-strided)
// u        : half[4][NN][16]  @ 14012288  (4 feature-quarter tables, 3.2MB each)
// hb       : float[NN*64]     @ 26812288
// tmp      : int[NBK*CAP]     @ 26812288  (overlaps hb; consumed before agg0)
// gsum     : float[4096]      @ 52412288
// gcnt     : float[64]        @ 52428672
// bcur     : int[NBK]         @ 52428928

static inline int cdiv_h(int a, int b) { return (a + b - 1) / b; }

struct H4 { __half2 a, b; };  // 8 bytes = 4 fp16 features

// ---- partition edges into fixed-capacity buckets (98 blocks x 16384 edges) ----
// LDS histogram -> one global reservation per (block,bucket) -> contiguous runs.
// Entry packed: (src << 8) | (dst & 255); src < 2^17 so fits 25 bits.
__global__ __launch_bounds__(256) void bplace_kernel(const int* __restrict__ ei,
                                                     int* __restrict__ bcur,
                                                     int* __restrict__ tmp) {
    __shared__ int h[NBK];
    __shared__ int boff[NBK];
    for (int t = threadIdx.x; t < NBK; t += 256) h[t] = 0;
    __syncthreads();
    int base = blockIdx.x * 16384;
#pragma unroll 4
    for (int i = 0; i < 64; i++) {
        int e = base + i * 256 + threadIdx.x;
        if (e < EE) atomicAdd(&h[ei[EE + e] >> 8], 1);
    }
    __syncthreads();
    for (int t = threadIdx.x; t < NBK; t += 256) {
        int c = h[t];
        boff[t] = c ? (t * CAP + atomicAdd(&bcur[t], c)) : 0;
        h[t] = 0;  // reuse as running cursor
    }
    __syncthreads();
#pragma unroll 4
    for (int i = 0; i < 64; i++) {
        int e = base + i * 256 + threadIdx.x;
        if (e < EE) {
            int s0 = ei[e];
            int d = ei[EE + e];
            int b = d >> 8;
            int p = boff[b] + atomicAdd(&h[b], 1);
            tmp[p] = (s0 << 8) | (d & 255);
        }
    }
}

// ---- per-bucket counting sort: srcs (bucket-strided CSR), rowStart/Len, dinv ----
__global__ __launch_bounds__(256) void bsort_kernel(const int* __restrict__ tmp,
                                                    const int* __restrict__ bcur,
                                                    int* __restrict__ rowStart,
                                                    int* __restrict__ rowLen,
                                                    float* __restrict__ dinv,
                                                    int* __restrict__ srcs) {
    int b = blockIdx.x;
    int n0 = b << 8;
    int e0 = b * CAP;
    int e1 = e0 + bcur[b];
    int t = threadIdx.x;
    __shared__ int cnt[256];
    __shared__ int st[256];
    cnt[t] = 0;
    __syncthreads();
    for (int e = e0 + t; e < e1; e += 256) atomicAdd(&cnt[tmp[e] & 255], 1);
    __syncthreads();
    int v = cnt[t];
    st[t] = v;
    __syncthreads();
    for (int off = 1; off < 256; off <<= 1) {
        int w = (t >= off) ? st[t - off] : 0;
        __syncthreads();
        st[t] += w;
        __syncthreads();
    }
    int excl = st[t] - v;
    int n = n0 + t;
    if (n < NN) {
        rowStart[n] = e0 + excl;
        rowLen[n] = v;
        dinv[n] = rsqrtf((float)v + 1.0f);
    }
    __syncthreads();
    cnt[t] = e0 + excl;  // absolute cursor
    __syncthreads();
    for (int e = e0 + t; e < e1; e += 256) {
        int p = tmp[e];
        int pos = atomicAdd(&cnt[p & 255], 1);
        srcs[pos] = p >> 8;
    }
}

// ---- gcnt: parallel LDS histogram over sorted batch ids ----
__global__ __launch_bounds__(256) void gcnt_kernel(const int* __restrict__ batch,
                                                   float* __restrict__ gcnt) {
    __shared__ int h[GG];
    if (threadIdx.x < GG) h[threadIdx.x] = 0;
    __syncthreads();
    int n = blockIdx.x * 256 + threadIdx.x;
    if (n < NN) atomicAdd(&h[batch[n]], 1);
    __syncthreads();
    if (threadIdx.x < GG && h[threadIdx.x])
        atomicAdd(&gcnt[threadIdx.x], (float)h[threadIdx.x]);
}

// u[q][n][:] = (half) dinv[n] * (hin[n][:] @ W) quarter q  -- one thread per row
__global__ __launch_bounds__(256) void gemm_kernel(const float* __restrict__ hin,
                                                   const float* __restrict__ Wg,
                                                   const float* __restrict__ dinv,
                                                   __half* __restrict__ u) {
    int n = blockIdx.x * 256 + threadIdx.x;
    if (n >= NN) return;
    const float* hr = hin + (size_t)n * 64;
    float acc[64];
#pragma unroll
    for (int j = 0; j < 64; j++) acc[j] = 0.0f;
#pragma unroll 2
    for (int k = 0; k < 64; k++) {
        float hk = hr[k];
        const float4* Wr = (const float4*)(Wg + (k << 6));
#pragma unroll
        for (int j = 0; j < 16; j++) {
            float4 w = Wr[j];
            acc[j * 4 + 0] = fmaf(hk, w.x, acc[j * 4 + 0]);
            acc[j * 4 + 1] = fmaf(hk, w.y, acc[j * 4 + 1]);
            acc[j * 4 + 2] = fmaf(hk, w.z, acc[j * 4 + 2]);
            acc[j * 4 + 3] = fmaf(hk, w.w, acc[j * 4 + 3]);
        }
    }
    float dv = dinv[n];
#pragma unroll
    for (int q = 0; q < 4; q++) {
        __half2 hh[8];
#pragma unroll
        for (int j = 0; j < 8; j++)
            hh[j] = __floats2half2_rn(acc[q * 16 + 2 * j] * dv,
                                      acc[q * 16 + 2 * j + 1] * dv);
        float4* dst = (float4*)(u + ((size_t)q * NN + n) * 16);
        dst[0] = *(float4*)&hh[0];
        dst[1] = *(float4*)&hh[4];
    }
}

// ---- quarter gather: 4 lanes/edge (8B each = 16-feature quarter row),
// 16 edges per load instruction; sub = lane>>2 in [0,16), fl = lane&3.
__device__ __forceinline__ void gatherq(const __half* __restrict__ uq,
                                        const int* __restrict__ srcs,
                                        int n, int sub, int fl, int rs, int len,
                                        float& a0, float& a1, float& a2, float& a3) {
    a0 = a1 = a2 = a3 = 0.0f;
    if (sub == 0) {
        H4 r = *(const H4*)(uq + (size_t)n * 16 + fl * 4);
        float2 f0 = __half22float2(r.a), f1 = __half22float2(r.b);
        a0 = f0.x; a1 = f0.y; a2 = f1.x; a3 = f1.y;
    }
    int e = rs + sub, end = rs + len;
    for (; e + 16 < end; e += 32) {
        int sA = srcs[e];
        int sB = srcs[e + 16];
        H4 ra = *(const H4*)(uq + (size_t)sA * 16 + fl * 4);
        H4 rb = *(const H4*)(uq + (size_t)sB * 16 + fl * 4);
        float2 fa0 = __half22float2(ra.a), fa1 = __half22float2(ra.b);
        float2 fb0 = __half22float2(rb.a), fb1 = __half22float2(rb.b);
        a0 += fa0.x; a1 += fa0.y; a2 += fa1.x; a3 += fa1.y;
        a0 += fb0.x; a1 += fb0.y; a2 += fb1.x; a3 += fb1.y;
    }
    if (e < end) {
        int sA = srcs[e];
        H4 ra = *(const H4*)(uq + (size_t)sA * 16 + fl * 4);
        float2 fa0 = __half22float2(ra.a), fa1 = __half22float2(ra.b);
        a0 += fa0.x; a1 += fa0.y; a2 += fa1.x; a3 += fa1.y;
    }
}

__device__ __forceinline__ void sub_reduce16(float& a0, float& a1, float& a2, float& a3) {
    a0 += __shfl_xor(a0, 4);  a1 += __shfl_xor(a1, 4);
    a2 += __shfl_xor(a2, 4);  a3 += __shfl_xor(a3, 4);
    a0 += __shfl_xor(a0, 8);  a1 += __shfl_xor(a1, 8);
    a2 += __shfl_xor(a2, 8);  a3 += __shfl_xor(a3, 8);
    a0 += __shfl_xor(a0, 16); a1 += __shfl_xor(a1, 16);
    a2 += __shfl_xor(a2, 16); a3 += __shfl_xor(a3, 16);
    a0 += __shfl_xor(a0, 32); a1 += __shfl_xor(a1, 32);
    a2 += __shfl_xor(a2, 32); a3 += __shfl_xor(a3, 32);
}

// layers 0,1: quarter q = blockIdx&3 (round-robin XCD => one 3.2MB table per XCD L2)
__global__ __launch_bounds__(256) void agg_kernel(const __half* __restrict__ u,
                                                  const int* __restrict__ srcs,
                                                  const int* __restrict__ rowStart,
                                                  const int* __restrict__ rowLen,
                                                  const float* __restrict__ dinv,
                                                  const float* __restrict__ bias,
                                                  float* __restrict__ hout) {
    int q = blockIdx.x & 3;
    int n = (blockIdx.x >> 2) * 4 + (threadIdx.x >> 6);
    int lane = threadIdx.x & 63;
    int sub = lane >> 2, fl = lane & 3;
    const __half* uq = u + (size_t)q * NN * 16;
    float a0, a1, a2, a3;
    gatherq(uq, srcs, n, sub, fl, rowStart[n], rowLen[n], a0, a1, a2, a3);
    sub_reduce16(a0, a1, a2, a3);
    if (sub == 0) {
        float dv = dinv[n];
        float4 bb = *(const float4*)(bias + q * 16 + fl * 4);
        float4 r;
        r.x = fmaxf(fmaf(dv, a0, bb.x), 0.0f);
        r.y = fmaxf(fmaf(dv, a1, bb.y), 0.0f);
        r.z = fmaxf(fmaf(dv, a2, bb.z), 0.0f);
        r.w = fmaxf(fmaf(dv, a3, bb.w), 0.0f);
        *(float4*)(hout + (size_t)n * 64 + q * 16 + fl * 4) = r;
    }
}

// layer 2 fused with mean-pool partial sums (per feature-quarter)
__global__ __launch_bounds__(256) void agg_pool_kernel(const __half* __restrict__ u,
                                                       const int* __restrict__ srcs,
                                                       const int* __restrict__ rowStart,
                                                       const int* __restrict__ rowLen,
                                                       const float* __restrict__ dinv,
                                                       const float* __restrict__ bias,
                                                       const int* __restrict__ batch,
                                                       float* __restrict__ gsum) {
    int q = blockIdx.x & 3;
    int n = (blockIdx.x >> 2) * 4 + (threadIdx.x >> 6);
    int w = threadIdx.x >> 6;
    int lane = threadIdx.x & 63;
    int sub = lane >> 2, fl = lane & 3;
    const __half* uq = u + (size_t)q * NN * 16;
    __shared__ float vals[4][16];
    __shared__ int gid[4];
    float a0, a1, a2, a3;
    gatherq(uq, srcs, n, sub, fl, rowStart[n], rowLen[n], a0, a1, a2, a3);
    sub_reduce16(a0, a1, a2, a3);
    if (sub == 0) {
        float dv = dinv[n];
        float4 bb = *(const float4*)(bias + q * 16 + fl * 4);
        float4 r;
        r.x = fmaxf(fmaf(dv, a0, bb.x), 0.0f);
        r.y = fmaxf(fmaf(dv, a1, bb.y), 0.0f);
        r.z = fmaxf(fmaf(dv, a2, bb.z), 0.0f);
        r.w = fmaxf(fmaf(dv, a3, bb.w), 0.0f);
        *(float4*)(&vals[w][fl * 4]) = r;
    }
    if (lane == 0) gid[w] = batch[n];
    __syncthreads();
    if (w == 0 && lane < 16) {
#pragma unroll
        for (int j = 0; j < 4; j++) {
            int gj = gid[j];
            bool first = true;
#pragma unroll
            for (int k = 0; k < 4; k++)
                if (k < j && gid[k] == gj) first = false;
            if (first) {
                float s = vals[j][lane];
#pragma unroll
                for (int k = 0; k < 4; k++)
                    if (k > j && gid[k] == gj) s += vals[k][lane];
                atomicAdd(&gsum[gj * 64 + q * 16 + lane], s);
            }
        }
    }
}

__global__ __launch_bounds__(128) void final_kernel(const float* __restrict__ gsum,
                                                    const float* __restrict__ gcnt,
                                                    const float* __restrict__ Wlin,
                                                    const float* __restrict__ blin,
                                                    float* __restrict__ out) {
    int t = threadIdx.x;  // 128 = G*C
    int g = t >> 1;
    int c = t & 1;
    float cnt = fmaxf(gcnt[g], 1.0f);
    float s = 0.0f;
#pragma unroll
    for (int k = 0; k < 64; k++) s = fmaf(gsum[g * 64 + k], Wlin[k * 2 + c], s);
    out[t] = s / cnt + blin[c];
}

extern "C" void kernel_launch(void* const* d_in, const int* in_sizes, int n_in,
                              void* d_out, int out_size, void* d_ws, size_t ws_size,
                              hipStream_t stream) {
    const float* x     = (const float*)d_in[0];
    const int*   ei    = (const int*)d_in[1];
    const int*   batch = (const int*)d_in[2];
    const float* W0    = (const float*)d_in[3];
    const float* b0    = (const float*)d_in[4];
    const float* W1    = (const float*)d_in[5];
    const float* b1    = (const float*)d_in[6];
    const float* W2    = (const float*)d_in[7];
    const float* b2    = (const float*)d_in[8];
    const float* Wlin  = (const float*)d_in[9];
    const float* blin  = (const float*)d_in[10];
    float* out = (float*)d_out;

    char* ws = (char*)d_ws;
    int*    rowStart = (int*)(ws + 0);
    int*    rowLen   = (int*)(ws + 400000);
    float*  dinv     = (float*)(ws + 800000);
    int*    srcs     = (int*)(ws + 1200000);
    __half* u        = (__half*)(ws + 14012288);
    float*  hb       = (float*)(ws + 26812288);
    int*    tmp      = (int*)(ws + 26812288);  // overlaps hb; dead before agg0
    float*  gsum     = (float*)(ws + 52412288);
    float*  gcnt     = (float*)(ws + 52428672);
    int*    bcur     = (int*)(ws + 52428928);

    // zero gsum+gcnt+bcur (contiguous)
    hipMemsetAsync(ws + 52412288, 0, 18204, stream);

    // CSR build: fixed-capacity bucket partition -> per-bucket sort
    bplace_kernel<<<cdiv_h(EE, 16384), 256, 0, stream>>>(ei, bcur, tmp);
    bsort_kernel<<<NBK, 256, 0, stream>>>(tmp, bcur, rowStart, rowLen, dinv, srcs);
    gcnt_kernel<<<NBK, 256, 0, stream>>>(batch, gcnt);

    int gemm_blocks = cdiv_h(NN, 256);
    int agg_blocks = NN;  // (NN/4 node groups) x 4 feature quarters

    gemm_kernel<<<gemm_blocks, 256, 0, stream>>>(x, W0, dinv, u);
    agg_kernel<<<agg_blocks, 256, 0, stream>>>(u, srcs, rowStart, rowLen, dinv, b0, hb);
    gemm_kernel<<<gemm_blocks, 256, 0, stream>>>(hb, W1, dinv, u);
    agg_kernel<<<agg_blocks, 256, 0, stream>>>(u, srcs, rowStart, rowLen, dinv, b1, hb);
    gemm_kernel<<<gemm_blocks, 256, 0, stream>>>(hb, W2, dinv, u);
    agg_pool_kernel<<<agg_blocks, 256, 0, stream>>>(u, srcs, rowStart, rowLen, dinv, b2, batch, gsum);

    final_kernel<<<1, 128, 0, stream>>>(gsum, gcnt, Wlin, blin, out);
}

// Round 7
// 400.977 us; speedup vs baseline: 1.6018x; 1.6018x over previous
//
#include <hip/hip_runtime.h>
#include <hip/hip_fp16.h>

#define NN 100000
#define EE 1600000
#define HH 64
#define GG 64
#define NBK 391    // buckets of 256 nodes: dst>>8
#define CAP 8192   // fixed bucket capacity (mean load 4092, max ~4400)

// ---------------- workspace layout (bytes) ----------------
// rowStart : int[NN]          @ 0
// rowLen   : int[NN]          @ 400000
// dinv     : float[NN]        @ 800000
// srcs     : int[NBK*CAP]     @ 1200000   (bucket-strided)
// u        : half[4][NN][16]  @ 14012288  (4 feature-quarter tables, 3.2MB each)
// hb       : float[NN*64]     @ 26812288
// tmp      : int[NBK*CAP]     @ 26812288  (overlaps hb; consumed before agg0)
// gsum     : float[4096]      @ 52412288
// gcnt     : float[64]        @ 52428672
// bcur     : int[NBK]         @ 52428928

static inline int cdiv_h(int a, int b) { return (a + b - 1) / b; }

struct H4 { __half2 a, b; };  // 8 bytes = 4 fp16 features

// ---- partition edges into fixed-capacity buckets (98 blocks x 16384 edges) ----
__global__ __launch_bounds__(256) void bplace_kernel(const int* __restrict__ ei,
                                                     int* __restrict__ bcur,
                                                     int* __restrict__ tmp) {
    __shared__ int h[NBK];
    __shared__ int boff[NBK];
    for (int t = threadIdx.x; t < NBK; t += 256) h[t] = 0;
    __syncthreads();
    int base = blockIdx.x * 16384;
#pragma unroll 4
    for (int i = 0; i < 64; i++) {
        int e = base + i * 256 + threadIdx.x;
        if (e < EE) atomicAdd(&h[ei[EE + e] >> 8], 1);
    }
    __syncthreads();
    for (int t = threadIdx.x; t < NBK; t += 256) {
        int c = h[t];
        boff[t] = c ? (t * CAP + atomicAdd(&bcur[t], c)) : 0;
        h[t] = 0;  // reuse as running cursor
    }
    __syncthreads();
#pragma unroll 4
    for (int i = 0; i < 64; i++) {
        int e = base + i * 256 + threadIdx.x;
        if (e < EE) {
            int s0 = ei[e];
            int d = ei[EE + e];
            int b = d >> 8;
            int p = boff[b] + atomicAdd(&h[b], 1);
            tmp[p] = (s0 << 8) | (d & 255);
        }
    }
}

// ---- per-bucket counting sort: srcs (bucket-strided CSR), rowStart/Len, dinv ----
__global__ __launch_bounds__(256) void bsort_kernel(const int* __restrict__ tmp,
                                                    const int* __restrict__ bcur,
                                                    int* __restrict__ rowStart,
                                                    int* __restrict__ rowLen,
                                                    float* __restrict__ dinv,
                                                    int* __restrict__ srcs) {
    int b = blockIdx.x;
    int n0 = b << 8;
    int e0 = b * CAP;
    int e1 = e0 + bcur[b];
    int t = threadIdx.x;
    __shared__ int cnt[256];
    __shared__ int st[256];
    cnt[t] = 0;
    __syncthreads();
    for (int e = e0 + t; e < e1; e += 256) atomicAdd(&cnt[tmp[e] & 255], 1);
    __syncthreads();
    int v = cnt[t];
    st[t] = v;
    __syncthreads();
    for (int off = 1; off < 256; off <<= 1) {
        int w = (t >= off) ? st[t - off] : 0;
        __syncthreads();
        st[t] += w;
        __syncthreads();
    }
    int excl = st[t] - v;
    int n = n0 + t;
    if (n < NN) {
        rowStart[n] = e0 + excl;
        rowLen[n] = v;
        dinv[n] = rsqrtf((float)v + 1.0f);
    }
    __syncthreads();
    cnt[t] = e0 + excl;  // absolute cursor
    __syncthreads();
    for (int e = e0 + t; e < e1; e += 256) {
        int p = tmp[e];
        int pos = atomicAdd(&cnt[p & 255], 1);
        srcs[pos] = p >> 8;
    }
}

// ---- gcnt: parallel LDS histogram over sorted batch ids ----
__global__ __launch_bounds__(256) void gcnt_kernel(const int* __restrict__ batch,
                                                   float* __restrict__ gcnt) {
    __shared__ int h[GG];
    if (threadIdx.x < GG) h[threadIdx.x] = 0;
    __syncthreads();
    int n = blockIdx.x * 256 + threadIdx.x;
    if (n < NN) atomicAdd(&h[batch[n]], 1);
    __syncthreads();
    if (threadIdx.x < GG && h[threadIdx.x])
        atomicAdd(&gcnt[threadIdx.x], (float)h[threadIdx.x]);
}

// u[q][n][:] = (half) dinv[n] * (hin[n][:] @ W) quarter q  -- one thread per row
__global__ __launch_bounds__(256) void gemm_kernel(const float* __restrict__ hin,
                                                   const float* __restrict__ Wg,
                                                   const float* __restrict__ dinv,
                                                   __half* __restrict__ u) {
    int n = blockIdx.x * 256 + threadIdx.x;
    if (n >= NN) return;
    const float* hr = hin + (size_t)n * 64;
    float acc[64];
#pragma unroll
    for (int j = 0; j < 64; j++) acc[j] = 0.0f;
#pragma unroll 2
    for (int k = 0; k < 64; k++) {
        float hk = hr[k];
        const float4* Wr = (const float4*)(Wg + (k << 6));
#pragma unroll
        for (int j = 0; j < 16; j++) {
            float4 w = Wr[j];
            acc[j * 4 + 0] = fmaf(hk, w.x, acc[j * 4 + 0]);
            acc[j * 4 + 1] = fmaf(hk, w.y, acc[j * 4 + 1]);
            acc[j * 4 + 2] = fmaf(hk, w.z, acc[j * 4 + 2]);
            acc[j * 4 + 3] = fmaf(hk, w.w, acc[j * 4 + 3]);
        }
    }
    float dv = dinv[n];
#pragma unroll
    for (int q = 0; q < 4; q++) {
        __half2 hh[8];
#pragma unroll
        for (int j = 0; j < 8; j++)
            hh[j] = __floats2half2_rn(acc[q * 16 + 2 * j] * dv,
                                      acc[q * 16 + 2 * j + 1] * dv);
        float4* dst = (float4*)(u + ((size_t)q * NN + n) * 16);
        dst[0] = *(float4*)&hh[0];
        dst[1] = *(float4*)&hh[4];
    }
}

// ---- quarter gather, 4 nodes per wave ----
// lane = ng*16 + sub*4 + fl : ng = node in wave, sub = edge slot, fl = feature/4.
// Each load instruction covers 4 nodes x 4 edges x 8B = 16 edges.
__device__ __forceinline__ void gatherq4(const __half* __restrict__ uq,
                                         const int* __restrict__ srcs,
                                         int n, int sub, int fl, int rs, int len,
                                         float& a0, float& a1, float& a2, float& a3) {
    a0 = a1 = a2 = a3 = 0.0f;
    if (sub == 0) {
        H4 r = *(const H4*)(uq + (size_t)n * 16 + fl * 4);
        float2 f0 = __half22float2(r.a), f1 = __half22float2(r.b);
        a0 = f0.x; a1 = f0.y; a2 = f1.x; a3 = f1.y;
    }
    int e = rs + sub, end = rs + len;
    for (; e + 4 < end; e += 8) {
        int sA = srcs[e];
        int sB = srcs[e + 4];
        H4 ra = *(const H4*)(uq + (size_t)sA * 16 + fl * 4);
        H4 rb = *(const H4*)(uq + (size_t)sB * 16 + fl * 4);
        float2 fa0 = __half22float2(ra.a), fa1 = __half22float2(ra.b);
        float2 fb0 = __half22float2(rb.a), fb1 = __half22float2(rb.b);
        a0 += fa0.x; a1 += fa0.y; a2 += fa1.x; a3 += fa1.y;
        a0 += fb0.x; a1 += fb0.y; a2 += fb1.x; a3 += fb1.y;
    }
    if (e < end) {
        int sA = srcs[e];
        H4 ra = *(const H4*)(uq + (size_t)sA * 16 + fl * 4);
        float2 fa0 = __half22float2(ra.a), fa1 = __half22float2(ra.b);
        a0 += fa0.x; a1 += fa0.y; a2 += fa1.x; a3 += fa1.y;
    }
}

// sum over sub (lane bits 2-3)
__device__ __forceinline__ void sub_reduce4(float& a0, float& a1, float& a2, float& a3) {
    a0 += __shfl_xor(a0, 4); a1 += __shfl_xor(a1, 4);
    a2 += __shfl_xor(a2, 4); a3 += __shfl_xor(a3, 4);
    a0 += __shfl_xor(a0, 8); a1 += __shfl_xor(a1, 8);
    a2 += __shfl_xor(a2, 8); a3 += __shfl_xor(a3, 8);
}

// layers 0,1: block = 16 nodes x 1 quarter; q = blockIdx&3 (round-robin XCD
// => one 3.2MB quarter table resident per XCD L2 -- confirmed by R6 FETCH drop)
__global__ __launch_bounds__(256) void agg_kernel(const __half* __restrict__ u,
                                                  const int* __restrict__ srcs,
                                                  const int* __restrict__ rowStart,
                                                  const int* __restrict__ rowLen,
                                                  const float* __restrict__ dinv,
                                                  const float* __restrict__ bias,
                                                  float* __restrict__ hout) {
    int q = blockIdx.x & 3;
    int grp = blockIdx.x >> 2;
    int w = threadIdx.x >> 6;
    int lane = threadIdx.x & 63;
    int ng = lane >> 4;
    int sub = (lane >> 2) & 3;
    int fl = lane & 3;
    int n = grp * 16 + w * 4 + ng;  // NN divisible by 16: no guard needed
    const __half* uq = u + (size_t)q * NN * 16;
    int rs = rowStart[n], len = rowLen[n];
    float a0, a1, a2, a3;
    gatherq4(uq, srcs, n, sub, fl, rs, len, a0, a1, a2, a3);
    sub_reduce4(a0, a1, a2, a3);
    if (sub == 0) {
        float dv = dinv[n];
        float4 bb = *(const float4*)(bias + q * 16 + fl * 4);
        float4 r;
        r.x = fmaxf(fmaf(dv, a0, bb.x), 0.0f);
        r.y = fmaxf(fmaf(dv, a1, bb.y), 0.0f);
        r.z = fmaxf(fmaf(dv, a2, bb.z), 0.0f);
        r.w = fmaxf(fmaf(dv, a3, bb.w), 0.0f);
        *(float4*)(hout + (size_t)n * 64 + q * 16 + fl * 4) = r;
    }
}

// layer 2 fused with mean-pool partial sums (16 nodes x 1 quarter per block)
__global__ __launch_bounds__(256) void agg_pool_kernel(const __half* __restrict__ u,
                                                       const int* __restrict__ srcs,
                                                       const int* __restrict__ rowStart,
                                                       const int* __restrict__ rowLen,
                                                       const float* __restrict__ dinv,
                                                       const float* __restrict__ bias,
                                                       const int* __restrict__ batch,
                                                       float* __restrict__ gsum) {
    int q = blockIdx.x & 3;
    int grp = blockIdx.x >> 2;
    int w = threadIdx.x >> 6;
    int lane = threadIdx.x & 63;
    int ng = lane >> 4;
    int sub = (lane >> 2) & 3;
    int fl = lane & 3;
    int n = grp * 16 + w * 4 + ng;
    const __half* uq = u + (size_t)q * NN * 16;
    __shared__ float vals[16][16];
    __shared__ int gid[16];
    int rs = rowStart[n], len = rowLen[n];
    float a0, a1, a2, a3;
    gatherq4(uq, srcs, n, sub, fl, rs, len, a0, a1, a2, a3);
    sub_reduce4(a0, a1, a2, a3);
    if (sub == 0) {
        float dv = dinv[n];
        float4 bb = *(const float4*)(bias + q * 16 + fl * 4);
        float4 r;
        r.x = fmaxf(fmaf(dv, a0, bb.x), 0.0f);
        r.y = fmaxf(fmaf(dv, a1, bb.y), 0.0f);
        r.z = fmaxf(fmaf(dv, a2, bb.z), 0.0f);
        r.w = fmaxf(fmaf(dv, a3, bb.w), 0.0f);
        *(float4*)(&vals[w * 4 + ng][fl * 4]) = r;
    }
    if ((lane & 15) == 0) gid[w * 4 + ng] = batch[n];
    __syncthreads();
    // batch is sorted -> nodes in block form runs of equal graph id
    if (threadIdx.x < 16) {
        int t = threadIdx.x;
        float run = vals[0][t];
        int curg = gid[0];
        for (int j = 1; j < 16; j++) {
            int gj = gid[j];
            if (gj != curg) {
                atomicAdd(&gsum[curg * 64 + q * 16 + t], run);
                curg = gj;
                run = 0.0f;
            }
            run += vals[j][t];
        }
        atomicAdd(&gsum[curg * 64 + q * 16 + t], run);
    }
}

__global__ __launch_bounds__(128) void final_kernel(const float* __restrict__ gsum,
                                                    const float* __restrict__ gcnt,
                                                    const float* __restrict__ Wlin,
                                                    const float* __restrict__ blin,
                                                    float* __restrict__ out) {
    int t = threadIdx.x;  // 128 = G*C
    int g = t >> 1;
    int c = t & 1;
    float cnt = fmaxf(gcnt[g], 1.0f);
    float s = 0.0f;
#pragma unroll
    for (int k = 0; k < 64; k++) s = fmaf(gsum[g * 64 + k], Wlin[k * 2 + c], s);
    out[t] = s / cnt + blin[c];
}

extern "C" void kernel_launch(void* const* d_in, const int* in_sizes, int n_in,
                              void* d_out, int out_size, void* d_ws, size_t ws_size,
                              hipStream_t stream) {
    const float* x     = (const float*)d_in[0];
    const int*   ei    = (const int*)d_in[1];
    const int*   batch = (const int*)d_in[2];
    const float* W0    = (const float*)d_in[3];
    const float* b0    = (const float*)d_in[4];
    const float* W1    = (const float*)d_in[5];
    const float* b1    = (const float*)d_in[6];
    const float* W2    = (const float*)d_in[7];
    const float* b2    = (const float*)d_in[8];
    const float* Wlin  = (const float*)d_in[9];
    const float* blin  = (const float*)d_in[10];
    float* out = (float*)d_out;

    char* ws = (char*)d_ws;
    int*    rowStart = (int*)(ws + 0);
    int*    rowLen   = (int*)(ws + 400000);
    float*  dinv     = (float*)(ws + 800000);
    int*    srcs     = (int*)(ws + 1200000);
    __half* u        = (__half*)(ws + 14012288);
    float*  hb       = (float*)(ws + 26812288);
    int*    tmp      = (int*)(ws + 26812288);  // overlaps hb; dead before agg0
    float*  gsum     = (float*)(ws + 52412288);
    float*  gcnt     = (float*)(ws + 52428672);
    int*    bcur     = (int*)(ws + 52428928);

    // zero gsum+gcnt+bcur (contiguous)
    hipMemsetAsync(ws + 52412288, 0, 18204, stream);

    // CSR build: fixed-capacity bucket partition -> per-bucket sort
    bplace_kernel<<<cdiv_h(EE, 16384), 256, 0, stream>>>(ei, bcur, tmp);
    bsort_kernel<<<NBK, 256, 0, stream>>>(tmp, bcur, rowStart, rowLen, dinv, srcs);
    gcnt_kernel<<<NBK, 256, 0, stream>>>(batch, gcnt);

    int gemm_blocks = cdiv_h(NN, 256);
    int agg_blocks = (NN / 16) * 4;  // 6250 node-groups x 4 feature quarters

    gemm_kernel<<<gemm_blocks, 256, 0, stream>>>(x, W0, dinv, u);
    agg_kernel<<<agg_blocks, 256, 0, stream>>>(u, srcs, rowStart, rowLen, dinv, b0, hb);
    gemm_kernel<<<gemm_blocks, 256, 0, stream>>>(hb, W1, dinv, u);
    agg_kernel<<<agg_blocks, 256, 0, stream>>>(u, srcs, rowStart, rowLen, dinv, b1, hb);
    gemm_kernel<<<gemm_blocks, 256, 0, stream>>>(hb, W2, dinv, u);
    agg_pool_kernel<<<agg_blocks, 256, 0, stream>>>(u, srcs, rowStart, rowLen, dinv, b2, batch, gsum);

    final_kernel<<<1, 128, 0, stream>>>(gsum, gcnt, Wlin, blin, out);
}